// Round 4
// baseline (231.471 us; speedup 1.0000x reference)
//
#include <hip/hip_runtime.h>
#include <hip/hip_bf16.h>

typedef __attribute__((ext_vector_type(8))) short short8;
typedef __attribute__((ext_vector_type(4))) float f32x4;

__device__ __forceinline__ unsigned short f2bf(float f) {
    unsigned u = __float_as_uint(f);
    u += 0x7fffu + ((u >> 16) & 1u);   // RNE to bf16
    return (unsigned short)(u >> 16);
}

// product of two packed-bf16x2 words, repacked via truncation (1 v_perm)
__device__ __forceinline__ unsigned bfmul_trunc(unsigned a, unsigned b) {
    float al = __uint_as_float(a << 16);
    float ah = __uint_as_float(a & 0xffff0000u);
    float bl = __uint_as_float(b << 16);
    float bh = __uint_as_float(b & 0xffff0000u);
    unsigned pl = __float_as_uint(al * bl);
    unsigned ph = __float_as_uint(ah * bh);
    return __builtin_amdgcn_perm(ph, pl, 0x07060302u);  // hi16(ph)<<16 | hi16(pl)
}

__device__ __forceinline__ unsigned pack_trunc(float lo, float hi) {
    return __builtin_amdgcn_perm(__float_as_uint(hi), __float_as_uint(lo), 0x07060302u);
}

// v1b = bf16(z_out + z_self), v2b = bf16(z_in + z_self)
// 4 float4 chunks per thread, all 12 loads issued before any use -> 12
// outstanding 16B loads/lane (MLP; the old version had ~1 and ran at 2 TB/s).
__global__ __launch_bounds__(256) void prep_kernel(
    const float4* __restrict__ zin, const float4* __restrict__ zout,
    const float4* __restrict__ zself,
    ushort4* __restrict__ v1b, ushort4* __restrict__ v2b, int n4)
{
    const int base = blockIdx.x * 1024 + threadIdx.x;
    float4 o[4], s[4], z[4];
#pragma unroll
    for (int u = 0; u < 4; u++) {
        int i = base + u * 256;
        if (i < n4) { o[u] = zout[i]; s[u] = zself[i]; z[u] = zin[i]; }
    }
#pragma unroll
    for (int u = 0; u < 4; u++) {
        int i = base + u * 256;
        if (i < n4) {
            ushort4 a, b;
            a.x = f2bf(o[u].x + s[u].x); a.y = f2bf(o[u].y + s[u].y);
            a.z = f2bf(o[u].z + s[u].z); a.w = f2bf(o[u].w + s[u].w);
            b.x = f2bf(z[u].x + s[u].x); b.y = f2bf(z[u].y + s[u].y);
            b.z = f2bf(z[u].z + s[u].z); b.w = f2bf(z[u].w + s[u].w);
            v1b[i] = a; v2b[i] = b;
        }
    }
}

// Pipelined edge kernel. One wave per 16-edge tile per iteration.
// W1 lives in LDS (fragment-major, ds_read_b128) to keep total regs < 128
// -> 16 waves/CU. Next tile's idx+gathers are issued before the current
// tile's MFMA/epilogue so 8 loads/wave stay in flight ~all the time.
__global__ __launch_bounds__(256, 4) void edge_pipe(
    const unsigned short* __restrict__ v1b, const unsigned short* __restrict__ v2b,
    const int* __restrict__ idx,
    const float* __restrict__ W1, const float* __restrict__ b1,
    const float* __restrict__ W2, const float* __restrict__ b2,
    float* __restrict__ out, int E, int ntiles)
{
    // 16 fragments (kc*4+jt) x 64 lanes x 8 bf16 = 16 KB, read as b128
    __shared__ __align__(16) unsigned short ldsW[16 * 64 * 8];

    const int tid  = threadIdx.x;
    const int wave = tid >> 6;
    const int lane = tid & 63;
    const int nn = lane & 15;   // edge-in-tile for A; column for B/D
    const int q  = lane >> 4;   // quad

    // stage W1 -> LDS in MFMA B-fragment layout:
    // frag f=(kc*4+jt), lane l holds t=0..7 of B[k=kc*32+(l>>4)*8+t][n=jt*16+(l&15)]
#pragma unroll
    for (int i = 0; i < 4; i++) {
        int p = tid * 4 + i;            // 0..1023 (frag,lane) pairs
        int f = p >> 6, l = p & 63;
        int kc = f >> 2, jt = f & 3, lq = (l >> 4) & 3, ln = l & 15;
        const float* wp = W1 + (size_t)(kc * 32 + lq * 8) * 64 + jt * 16 + ln;
        uint4 wv;
        wv.x = (unsigned)f2bf(wp[0 * 64]) | ((unsigned)f2bf(wp[1 * 64]) << 16);
        wv.y = (unsigned)f2bf(wp[2 * 64]) | ((unsigned)f2bf(wp[3 * 64]) << 16);
        wv.z = (unsigned)f2bf(wp[4 * 64]) | ((unsigned)f2bf(wp[5 * 64]) << 16);
        wv.w = (unsigned)f2bf(wp[6 * 64]) | ((unsigned)f2bf(wp[7 * 64]) << 16);
        *(uint4*)&ldsW[p * 8] = wv;
    }
    __syncthreads();

    float bias1[4], w2v[4];
#pragma unroll
    for (int jt = 0; jt < 4; jt++) {
        bias1[jt] = b1[jt * 16 + nn];
        w2v[jt]   = W2[jt * 16 + nn];
    }
    const float b2v = b2[0];

    const int nwaves = gridDim.x * 4;
    int tile = blockIdx.x * 4 + wave;
    if (tile >= ntiles) return;

    // pipeline prologue: idx + gathers for first tile
    int ee  = min(tile * 16 + nn, E - 1);
    int src = idx[ee];
    int dst = idx[E + ee];
    uint4 a[4], b[4];
    {
        const uint4* p1 = (const uint4*)(v1b + (size_t)src * 128);
        const uint4* p2 = (const uint4*)(v2b + (size_t)dst * 128);
#pragma unroll
        for (int kc = 0; kc < 4; kc++) { a[kc] = p1[kc * 4 + q]; b[kc] = p2[kc * 4 + q]; }
    }

    for (; tile < ntiles; tile += nwaves) {
        // issue next tile's idx load (in flight during product compute)
        const int tn = tile + nwaves;
        const int tt = (tn < ntiles) ? tn : tile;       // clamp: tail re-gathers self
        const int een  = min(tt * 16 + nn, E - 1);
        const int srcn = idx[een];
        const int dstn = idx[E + een];

        // products for current tile -> A fragments
        short8 Af[4];
#pragma unroll
        for (int kc = 0; kc < 4; kc++) {
            uint4 p;
            p.x = bfmul_trunc(a[kc].x, b[kc].x);
            p.y = bfmul_trunc(a[kc].y, b[kc].y);
            p.z = bfmul_trunc(a[kc].z, b[kc].z);
            p.w = bfmul_trunc(a[kc].w, b[kc].w);
            Af[kc] = __builtin_bit_cast(short8, p);
        }

        // issue next tile's gathers (raw regs now dead, reuse)
        {
            const uint4* p1 = (const uint4*)(v1b + (size_t)srcn * 128);
            const uint4* p2 = (const uint4*)(v2b + (size_t)dstn * 128);
#pragma unroll
            for (int kc = 0; kc < 4; kc++) { a[kc] = p1[kc * 4 + q]; b[kc] = p2[kc * 4 + q]; }
        }

        // MFMA: 16x 16x16x32 bf16, B fragments streamed from LDS
        f32x4 acc[4];
#pragma unroll
        for (int jt = 0; jt < 4; jt++) acc[jt] = (f32x4){0.f, 0.f, 0.f, 0.f};
#pragma unroll
        for (int kc = 0; kc < 4; kc++) {
#pragma unroll
            for (int jt = 0; jt < 4; jt++) {
                short8 Bf = *(const short8*)&ldsW[((kc * 4 + jt) * 64 + lane) * 8];
                acc[jt] = __builtin_amdgcn_mfma_f32_16x16x32_bf16(Af[kc], Bf, acc[jt], 0, 0, 0);
            }
        }

        // epilogue: h = ELU(acc + b1); partial = sum_n h * W2[n]
        float ps[4];
#pragma unroll
        for (int r = 0; r < 4; r++) {
            float s = 0.f;
#pragma unroll
            for (int jt = 0; jt < 4; jt++) {
                float h = acc[jt][r] + bias1[jt];
                h = (h > 0.f) ? h : (__expf(h) - 1.f);
                s += h * w2v[jt];
            }
            ps[r] = s;
        }
#pragma unroll
        for (int off = 1; off < 16; off <<= 1) {
#pragma unroll
            for (int r = 0; r < 4; r++)
                ps[r] += __shfl_xor(ps[r], off, 64);
        }
        if (nn == 0) {
#pragma unroll
            for (int r = 0; r < 4; r++) {
                int e = tile * 16 + q * 4 + r;   // D row = quad*4 + reg
                if (e < E) {
                    float x = ps[r] + b2v;
                    out[e] = 1.f / (1.f + __expf(-x));
                }
            }
        }
    }
}

// Fallback (ws too small): non-pipelined, gathers f32 z-arrays directly.
__global__ __launch_bounds__(256) void edge_f32(
    const float* __restrict__ zin, const float* __restrict__ zout,
    const float* __restrict__ zself,
    const int* __restrict__ idx,
    const float* __restrict__ W1, const float* __restrict__ b1,
    const float* __restrict__ W2, const float* __restrict__ b2,
    float* __restrict__ out, int E, int ntiles)
{
    const int wave = threadIdx.x >> 6;
    const int lane = threadIdx.x & 63;
    const int nn = lane & 15;
    const int q  = lane >> 4;

    short8 Bf[4][4];
#pragma unroll
    for (int kc = 0; kc < 4; kc++)
#pragma unroll
        for (int jt = 0; jt < 4; jt++) {
            short8 v;
#pragma unroll
            for (int t = 0; t < 8; t++)
                v[t] = (short)f2bf(W1[(kc * 32 + q * 8 + t) * 64 + jt * 16 + nn]);
            Bf[kc][jt] = v;
        }
    float bias1[4], w2v[4];
#pragma unroll
    for (int jt = 0; jt < 4; jt++) {
        bias1[jt] = b1[jt * 16 + nn];
        w2v[jt]   = W2[jt * 16 + nn];
    }
    const float b2v = b2[0];

    const int nwaves = gridDim.x * 4;
    for (int tile = blockIdx.x * 4 + wave; tile < ntiles; tile += nwaves) {
        const int ebase = tile * 16;
        const int ee  = min(ebase + nn, E - 1);
        const int src = idx[ee];
        const int dst = idx[E + ee];

        short8 Af[4];
        const float* po  = zout  + (size_t)src * 128 + q * 8;
        const float* ps1 = zself + (size_t)src * 128 + q * 8;
        const float* pi  = zin   + (size_t)dst * 128 + q * 8;
        const float* ps2 = zself + (size_t)dst * 128 + q * 8;
#pragma unroll
        for (int kc = 0; kc < 4; kc++) {
            float4 oa = *(const float4*)(po  + kc * 32), ob = *(const float4*)(po  + kc * 32 + 4);
            float4 sa = *(const float4*)(ps1 + kc * 32), sb = *(const float4*)(ps1 + kc * 32 + 4);
            float4 ia = *(const float4*)(pi  + kc * 32), ib = *(const float4*)(pi  + kc * 32 + 4);
            float4 ta = *(const float4*)(ps2 + kc * 32), tb = *(const float4*)(ps2 + kc * 32 + 4);
            uint4 p;
            p.x = pack_trunc((oa.x + sa.x) * (ia.x + ta.x), (oa.y + sa.y) * (ia.y + ta.y));
            p.y = pack_trunc((oa.z + sa.z) * (ia.z + ta.z), (oa.w + sa.w) * (ia.w + ta.w));
            p.z = pack_trunc((ob.x + sb.x) * (ib.x + tb.x), (ob.y + sb.y) * (ib.y + tb.y));
            p.w = pack_trunc((ob.z + sb.z) * (ib.z + tb.z), (ob.w + sb.w) * (ib.w + tb.w));
            Af[kc] = __builtin_bit_cast(short8, p);
        }

        f32x4 acc[4];
#pragma unroll
        for (int jt = 0; jt < 4; jt++) acc[jt] = (f32x4){0.f, 0.f, 0.f, 0.f};
#pragma unroll
        for (int kc = 0; kc < 4; kc++)
#pragma unroll
            for (int jt = 0; jt < 4; jt++)
                acc[jt] = __builtin_amdgcn_mfma_f32_16x16x32_bf16(Af[kc], Bf[kc][jt], acc[jt], 0, 0, 0);

        float ps[4];
#pragma unroll
        for (int r = 0; r < 4; r++) {
            float s = 0.f;
#pragma unroll
            for (int jt = 0; jt < 4; jt++) {
                float h = acc[jt][r] + bias1[jt];
                h = (h > 0.f) ? h : (__expf(h) - 1.f);
                s += h * w2v[jt];
            }
            ps[r] = s;
        }
#pragma unroll
        for (int off = 1; off < 16; off <<= 1) {
#pragma unroll
            for (int r = 0; r < 4; r++)
                ps[r] += __shfl_xor(ps[r], off, 64);
        }
        if (nn == 0) {
#pragma unroll
            for (int r = 0; r < 4; r++) {
                int e = ebase + q * 4 + r;
                if (e < E) {
                    float x = ps[r] + b2v;
                    out[e] = 1.f / (1.f + __expf(-x));
                }
            }
        }
    }
}

extern "C" void kernel_launch(void* const* d_in, const int* in_sizes, int n_in,
                              void* d_out, int out_size, void* d_ws, size_t ws_size,
                              hipStream_t stream)
{
    const float* zin   = (const float*)d_in[0];
    const float* zout  = (const float*)d_in[1];
    const float* zself = (const float*)d_in[2];
    const int*   idx   = (const int*)d_in[3];
    const float* W1    = (const float*)d_in[4];
    const float* b1    = (const float*)d_in[5];
    const float* W2    = (const float*)d_in[6];
    const float* b2    = (const float*)d_in[7];
    float* out = (float*)d_out;

    const int NC = in_sizes[0];          // N*C
    const int E  = in_sizes[3] / 2;
    const int ntiles = (E + 15) / 16;
    const size_t need = (size_t)NC * 4;  // two bf16 [N,C] arrays

    if (ws_size >= need) {
        unsigned short* v1b = (unsigned short*)d_ws;
        unsigned short* v2b = v1b + NC;
        const int n4 = NC / 4;
        prep_kernel<<<(n4 + 1023) / 1024, 256, 0, stream>>>(
            (const float4*)zin, (const float4*)zout, (const float4*)zself,
            (ushort4*)v1b, (ushort4*)v2b, n4);
        edge_pipe<<<1024, 256, 0, stream>>>(
            v1b, v2b, idx, W1, b1, W2, b2, out, E, ntiles);
    } else {
        edge_f32<<<2048, 256, 0, stream>>>(
            zin, zout, zself, idx, W1, b1, W2, b2, out, E, ntiles);
    }
}

// Round 5
// 231.367 us; speedup vs baseline: 1.0004x; 1.0004x over previous
//
#include <hip/hip_runtime.h>
#include <hip/hip_bf16.h>

typedef __attribute__((ext_vector_type(8))) short short8;
typedef __attribute__((ext_vector_type(4))) float f32x4;

__device__ __forceinline__ unsigned short f2bf(float f) {
    unsigned u = __float_as_uint(f);
    u += 0x7fffu + ((u >> 16) & 1u);   // RNE to bf16
    return (unsigned short)(u >> 16);
}

// product of two packed-bf16x2 words, repacked via truncation (1 v_perm)
__device__ __forceinline__ unsigned bfmul_trunc(unsigned a, unsigned b) {
    float al = __uint_as_float(a << 16);
    float ah = __uint_as_float(a & 0xffff0000u);
    float bl = __uint_as_float(b << 16);
    float bh = __uint_as_float(b & 0xffff0000u);
    unsigned pl = __float_as_uint(al * bl);
    unsigned ph = __float_as_uint(ah * bh);
    return __builtin_amdgcn_perm(ph, pl, 0x07060302u);  // hi16(ph)<<16 | hi16(pl)
}

__device__ __forceinline__ unsigned pack_trunc(float lo, float hi) {
    return __builtin_amdgcn_perm(__float_as_uint(hi), __float_as_uint(lo), 0x07060302u);
}

// v1b = bf16(z_out + z_self), v2b = bf16(z_in + z_self)
// Full blocks (blockIdx < nfull) run a guard-free path: 12 unconditional
// independent 16B loads issued back-to-back, so ~9-12 stay in flight per
// wave (round-4's guarded loads collapsed to ~3 -> 2 TB/s).
__global__ __launch_bounds__(256) void prep_kernel(
    const float4* __restrict__ zin, const float4* __restrict__ zout,
    const float4* __restrict__ zself,
    ushort4* __restrict__ v1b, ushort4* __restrict__ v2b, int n4, int nfull)
{
    const int base = blockIdx.x * 1024 + threadIdx.x;
    if (blockIdx.x < nfull) {
        float4 o[4], s[4], z[4];
#pragma unroll
        for (int u = 0; u < 4; u++) {
            const int i = base + u * 256;
            o[u] = zout[i]; s[u] = zself[i]; z[u] = zin[i];
        }
#pragma unroll
        for (int u = 0; u < 4; u++) {
            const int i = base + u * 256;
            ushort4 a, b;
            a.x = f2bf(o[u].x + s[u].x); a.y = f2bf(o[u].y + s[u].y);
            a.z = f2bf(o[u].z + s[u].z); a.w = f2bf(o[u].w + s[u].w);
            b.x = f2bf(z[u].x + s[u].x); b.y = f2bf(z[u].y + s[u].y);
            b.z = f2bf(z[u].z + s[u].z); b.w = f2bf(z[u].w + s[u].w);
            v1b[i] = a; v2b[i] = b;
        }
    } else {
#pragma unroll
        for (int u = 0; u < 4; u++) {
            const int i = base + u * 256;
            if (i < n4) {
                float4 o = zout[i], s = zself[i], z = zin[i];
                ushort4 a, b;
                a.x = f2bf(o.x + s.x); a.y = f2bf(o.y + s.y);
                a.z = f2bf(o.z + s.z); a.w = f2bf(o.w + s.w);
                b.x = f2bf(z.x + s.x); b.y = f2bf(z.y + s.y);
                b.z = f2bf(z.z + s.z); b.w = f2bf(z.w + s.w);
                v1b[i] = a; v2b[i] = b;
            }
        }
    }
}

// Pipelined edge kernel. One wave per 16-edge tile per iteration.
// W1 lives in LDS (fragment-major, ds_read_b128) to keep total regs < 128
// -> 16 waves/CU. Next tile's idx+gathers are issued before the current
// tile's MFMA/epilogue so 8 loads/wave stay in flight ~all the time.
__global__ __launch_bounds__(256, 4) void edge_pipe(
    const unsigned short* __restrict__ v1b, const unsigned short* __restrict__ v2b,
    const int* __restrict__ idx,
    const float* __restrict__ W1, const float* __restrict__ b1,
    const float* __restrict__ W2, const float* __restrict__ b2,
    float* __restrict__ out, int E, int ntiles)
{
    // 16 fragments (kc*4+jt) x 64 lanes x 8 bf16 = 16 KB, read as b128
    __shared__ __align__(16) unsigned short ldsW[16 * 64 * 8];

    const int tid  = threadIdx.x;
    const int wave = tid >> 6;
    const int lane = tid & 63;
    const int nn = lane & 15;   // edge-in-tile for A; column for B/D
    const int q  = lane >> 4;   // quad

    // stage W1 -> LDS in MFMA B-fragment layout:
    // frag f=(kc*4+jt), lane l holds t=0..7 of B[k=kc*32+(l>>4)*8+t][n=jt*16+(l&15)]
#pragma unroll
    for (int i = 0; i < 4; i++) {
        int p = tid * 4 + i;            // 0..1023 (frag,lane) pairs
        int f = p >> 6, l = p & 63;
        int kc = f >> 2, jt = f & 3, lq = (l >> 4) & 3, ln = l & 15;
        const float* wp = W1 + (size_t)(kc * 32 + lq * 8) * 64 + jt * 16 + ln;
        uint4 wv;
        wv.x = (unsigned)f2bf(wp[0 * 64]) | ((unsigned)f2bf(wp[1 * 64]) << 16);
        wv.y = (unsigned)f2bf(wp[2 * 64]) | ((unsigned)f2bf(wp[3 * 64]) << 16);
        wv.z = (unsigned)f2bf(wp[4 * 64]) | ((unsigned)f2bf(wp[5 * 64]) << 16);
        wv.w = (unsigned)f2bf(wp[6 * 64]) | ((unsigned)f2bf(wp[7 * 64]) << 16);
        *(uint4*)&ldsW[p * 8] = wv;
    }
    __syncthreads();

    float bias1[4], w2v[4];
#pragma unroll
    for (int jt = 0; jt < 4; jt++) {
        bias1[jt] = b1[jt * 16 + nn];
        w2v[jt]   = W2[jt * 16 + nn];
    }
    const float b2v = b2[0];

    const int nwaves = gridDim.x * 4;
    int tile = blockIdx.x * 4 + wave;
    if (tile >= ntiles) return;

    // pipeline prologue: idx + gathers for first tile
    int ee  = min(tile * 16 + nn, E - 1);
    int src = idx[ee];
    int dst = idx[E + ee];
    uint4 a[4], b[4];
    {
        const uint4* p1 = (const uint4*)(v1b + (size_t)src * 128);
        const uint4* p2 = (const uint4*)(v2b + (size_t)dst * 128);
#pragma unroll
        for (int kc = 0; kc < 4; kc++) { a[kc] = p1[kc * 4 + q]; b[kc] = p2[kc * 4 + q]; }
    }

    for (; tile < ntiles; tile += nwaves) {
        // issue next tile's idx load (in flight during product compute)
        const int tn = tile + nwaves;
        const int tt = (tn < ntiles) ? tn : tile;       // clamp: tail re-gathers self
        const int een  = min(tt * 16 + nn, E - 1);
        const int srcn = idx[een];
        const int dstn = idx[E + een];

        // products for current tile -> A fragments
        short8 Af[4];
#pragma unroll
        for (int kc = 0; kc < 4; kc++) {
            uint4 p;
            p.x = bfmul_trunc(a[kc].x, b[kc].x);
            p.y = bfmul_trunc(a[kc].y, b[kc].y);
            p.z = bfmul_trunc(a[kc].z, b[kc].z);
            p.w = bfmul_trunc(a[kc].w, b[kc].w);
            Af[kc] = __builtin_bit_cast(short8, p);
        }

        // issue next tile's gathers (raw regs now dead, reuse)
        {
            const uint4* p1 = (const uint4*)(v1b + (size_t)srcn * 128);
            const uint4* p2 = (const uint4*)(v2b + (size_t)dstn * 128);
#pragma unroll
            for (int kc = 0; kc < 4; kc++) { a[kc] = p1[kc * 4 + q]; b[kc] = p2[kc * 4 + q]; }
        }

        // MFMA: 16x 16x16x32 bf16, B fragments streamed from LDS
        f32x4 acc[4];
#pragma unroll
        for (int jt = 0; jt < 4; jt++) acc[jt] = (f32x4){0.f, 0.f, 0.f, 0.f};
#pragma unroll
        for (int kc = 0; kc < 4; kc++) {
#pragma unroll
            for (int jt = 0; jt < 4; jt++) {
                short8 Bf = *(const short8*)&ldsW[((kc * 4 + jt) * 64 + lane) * 8];
                acc[jt] = __builtin_amdgcn_mfma_f32_16x16x32_bf16(Af[kc], Bf, acc[jt], 0, 0, 0);
            }
        }

        // epilogue: h = ELU(acc + b1); partial = sum_n h * W2[n]
        float ps[4];
#pragma unroll
        for (int r = 0; r < 4; r++) {
            float s = 0.f;
#pragma unroll
            for (int jt = 0; jt < 4; jt++) {
                float h = acc[jt][r] + bias1[jt];
                h = (h > 0.f) ? h : (__expf(h) - 1.f);
                s += h * w2v[jt];
            }
            ps[r] = s;
        }
#pragma unroll
        for (int off = 1; off < 16; off <<= 1) {
#pragma unroll
            for (int r = 0; r < 4; r++)
                ps[r] += __shfl_xor(ps[r], off, 64);
        }
        if (nn == 0) {
#pragma unroll
            for (int r = 0; r < 4; r++) {
                int e = tile * 16 + q * 4 + r;   // D row = quad*4 + reg
                if (e < E) {
                    float x = ps[r] + b2v;
                    out[e] = 1.f / (1.f + __expf(-x));
                }
            }
        }
    }
}

// Fallback (ws too small): non-pipelined, gathers f32 z-arrays directly.
__global__ __launch_bounds__(256) void edge_f32(
    const float* __restrict__ zin, const float* __restrict__ zout,
    const float* __restrict__ zself,
    const int* __restrict__ idx,
    const float* __restrict__ W1, const float* __restrict__ b1,
    const float* __restrict__ W2, const float* __restrict__ b2,
    float* __restrict__ out, int E, int ntiles)
{
    const int wave = threadIdx.x >> 6;
    const int lane = threadIdx.x & 63;
    const int nn = lane & 15;
    const int q  = lane >> 4;

    short8 Bf[4][4];
#pragma unroll
    for (int kc = 0; kc < 4; kc++)
#pragma unroll
        for (int jt = 0; jt < 4; jt++) {
            short8 v;
#pragma unroll
            for (int t = 0; t < 8; t++)
                v[t] = (short)f2bf(W1[(kc * 32 + q * 8 + t) * 64 + jt * 16 + nn]);
            Bf[kc][jt] = v;
        }
    float bias1[4], w2v[4];
#pragma unroll
    for (int jt = 0; jt < 4; jt++) {
        bias1[jt] = b1[jt * 16 + nn];
        w2v[jt]   = W2[jt * 16 + nn];
    }
    const float b2v = b2[0];

    const int nwaves = gridDim.x * 4;
    for (int tile = blockIdx.x * 4 + wave; tile < ntiles; tile += nwaves) {
        const int ebase = tile * 16;
        const int ee  = min(ebase + nn, E - 1);
        const int src = idx[ee];
        const int dst = idx[E + ee];

        short8 Af[4];
        const float* po  = zout  + (size_t)src * 128 + q * 8;
        const float* ps1 = zself + (size_t)src * 128 + q * 8;
        const float* pi  = zin   + (size_t)dst * 128 + q * 8;
        const float* ps2 = zself + (size_t)dst * 128 + q * 8;
#pragma unroll
        for (int kc = 0; kc < 4; kc++) {
            float4 oa = *(const float4*)(po  + kc * 32), ob = *(const float4*)(po  + kc * 32 + 4);
            float4 sa = *(const float4*)(ps1 + kc * 32), sb = *(const float4*)(ps1 + kc * 32 + 4);
            float4 ia = *(const float4*)(pi  + kc * 32), ib = *(const float4*)(pi  + kc * 32 + 4);
            float4 ta = *(const float4*)(ps2 + kc * 32), tb = *(const float4*)(ps2 + kc * 32 + 4);
            uint4 p;
            p.x = pack_trunc((oa.x + sa.x) * (ia.x + ta.x), (oa.y + sa.y) * (ia.y + ta.y));
            p.y = pack_trunc((oa.z + sa.z) * (ia.z + ta.z), (oa.w + sa.w) * (ia.w + ta.w));
            p.z = pack_trunc((ob.x + sb.x) * (ib.x + tb.x), (ob.y + sb.y) * (ib.y + tb.y));
            p.w = pack_trunc((ob.z + sb.z) * (ib.z + tb.z), (ob.w + sb.w) * (ib.w + tb.w));
            Af[kc] = __builtin_bit_cast(short8, p);
        }

        f32x4 acc[4];
#pragma unroll
        for (int jt = 0; jt < 4; jt++) acc[jt] = (f32x4){0.f, 0.f, 0.f, 0.f};
#pragma unroll
        for (int kc = 0; kc < 4; kc++)
#pragma unroll
            for (int jt = 0; jt < 4; jt++)
                acc[jt] = __builtin_amdgcn_mfma_f32_16x16x32_bf16(Af[kc], Bf[kc][jt], acc[jt], 0, 0, 0);

        float ps[4];
#pragma unroll
        for (int r = 0; r < 4; r++) {
            float s = 0.f;
#pragma unroll
            for (int jt = 0; jt < 4; jt++) {
                float h = acc[jt][r] + bias1[jt];
                h = (h > 0.f) ? h : (__expf(h) - 1.f);
                s += h * w2v[jt];
            }
            ps[r] = s;
        }
#pragma unroll
        for (int off = 1; off < 16; off <<= 1) {
#pragma unroll
            for (int r = 0; r < 4; r++)
                ps[r] += __shfl_xor(ps[r], off, 64);
        }
        if (nn == 0) {
#pragma unroll
            for (int r = 0; r < 4; r++) {
                int e = ebase + q * 4 + r;
                if (e < E) {
                    float x = ps[r] + b2v;
                    out[e] = 1.f / (1.f + __expf(-x));
                }
            }
        }
    }
}

extern "C" void kernel_launch(void* const* d_in, const int* in_sizes, int n_in,
                              void* d_out, int out_size, void* d_ws, size_t ws_size,
                              hipStream_t stream)
{
    const float* zin   = (const float*)d_in[0];
    const float* zout  = (const float*)d_in[1];
    const float* zself = (const float*)d_in[2];
    const int*   idx   = (const int*)d_in[3];
    const float* W1    = (const float*)d_in[4];
    const float* b1    = (const float*)d_in[5];
    const float* W2    = (const float*)d_in[6];
    const float* b2    = (const float*)d_in[7];
    float* out = (float*)d_out;

    const int NC = in_sizes[0];          // N*C
    const int E  = in_sizes[3] / 2;
    const int ntiles = (E + 15) / 16;
    const size_t need = (size_t)NC * 4;  // two bf16 [N,C] arrays

    if (ws_size >= need) {
        unsigned short* v1b = (unsigned short*)d_ws;
        unsigned short* v2b = v1b + NC;
        const int n4 = NC / 4;
        const int nblocks = (n4 + 1023) / 1024;
        const int nfull   = n4 / 1024;   // blocks with no bounds checks
        prep_kernel<<<nblocks, 256, 0, stream>>>(
            (const float4*)zin, (const float4*)zout, (const float4*)zself,
            (ushort4*)v1b, (ushort4*)v2b, n4, nfull);
        edge_pipe<<<1024, 256, 0, stream>>>(
            v1b, v2b, idx, W1, b1, W2, b2, out, E, ntiles);
    } else {
        edge_f32<<<2048, 256, 0, stream>>>(
            zin, zout, zself, idx, W1, b1, W2, b2, out, E, ntiles);
    }
}

// Round 6
// 228.965 us; speedup vs baseline: 1.0109x; 1.0105x over previous
//
#include <hip/hip_runtime.h>
#include <hip/hip_bf16.h>

typedef __attribute__((ext_vector_type(8))) short short8;
typedef __attribute__((ext_vector_type(4))) float f32x4;

__device__ __forceinline__ unsigned short f2bf(float f) {
    unsigned u = __float_as_uint(f);
    u += 0x7fffu + ((u >> 16) & 1u);   // RNE to bf16
    return (unsigned short)(u >> 16);
}

// product of two packed-bf16x2 words, repacked via truncation (1 v_perm)
__device__ __forceinline__ unsigned bfmul_trunc(unsigned a, unsigned b) {
    float al = __uint_as_float(a << 16);
    float ah = __uint_as_float(a & 0xffff0000u);
    float bl = __uint_as_float(b << 16);
    float bh = __uint_as_float(b & 0xffff0000u);
    unsigned pl = __float_as_uint(al * bl);
    unsigned ph = __float_as_uint(ah * bh);
    return __builtin_amdgcn_perm(ph, pl, 0x07060302u);  // hi16(ph)<<16 | hi16(pl)
}

__device__ __forceinline__ unsigned pack_trunc(float lo, float hi) {
    return __builtin_amdgcn_perm(__float_as_uint(hi), __float_as_uint(lo), 0x07060302u);
}

// v1b = bf16(z_out + z_self), v2b = bf16(z_in + z_self)
// launch_bounds(256, 1): license the allocator to keep all 12 x 16B loads
// live (rounds 3-5 proved the default heuristic sinks them to VGPR=32 and
// ~1 load in flight -> 2 TB/s). sched_barrier(0) walls loads off from uses.
__global__ __launch_bounds__(256, 1) void prep_kernel(
    const float4* __restrict__ zin, const float4* __restrict__ zout,
    const float4* __restrict__ zself,
    ushort4* __restrict__ v1b, ushort4* __restrict__ v2b, int n4)
{
    const int base = blockIdx.x * 1024 + threadIdx.x;
    const bool full = (blockIdx.x + 1) * 1024 <= n4;   // whole block in-range
    if (full) {
        float4 o[4], s[4], z[4];
#pragma unroll
        for (int u = 0; u < 4; u++) {
            const int i = base + u * 256;
            o[u] = zout[i]; s[u] = zself[i]; z[u] = zin[i];
        }
        __builtin_amdgcn_sched_barrier(0);   // all 12 loads issue before any use
#pragma unroll
        for (int u = 0; u < 4; u++) {
            const int i = base + u * 256;
            ushort4 a, b;
            a.x = f2bf(o[u].x + s[u].x); a.y = f2bf(o[u].y + s[u].y);
            a.z = f2bf(o[u].z + s[u].z); a.w = f2bf(o[u].w + s[u].w);
            b.x = f2bf(z[u].x + s[u].x); b.y = f2bf(z[u].y + s[u].y);
            b.z = f2bf(z[u].z + s[u].z); b.w = f2bf(z[u].w + s[u].w);
            v1b[i] = a; v2b[i] = b;
        }
    } else {
#pragma unroll
        for (int u = 0; u < 4; u++) {
            const int i = base + u * 256;
            if (i < n4) {
                float4 o = zout[i], s = zself[i], z = zin[i];
                ushort4 a, b;
                a.x = f2bf(o.x + s.x); a.y = f2bf(o.y + s.y);
                a.z = f2bf(o.z + s.z); a.w = f2bf(o.w + s.w);
                b.x = f2bf(z.x + s.x); b.y = f2bf(z.y + s.y);
                b.z = f2bf(z.z + s.z); b.w = f2bf(z.w + s.w);
                v1b[i] = a; v2b[i] = b;
            }
        }
    }
}

// Pipelined edge kernel. One wave per 16-edge tile per iteration.
// W1 lives in LDS (fragment-major, ds_read_b128) to keep total regs < 128
// -> 16 waves/CU. Next tile's idx+gathers are issued before the current
// tile's MFMA/epilogue so 8 loads/wave stay in flight ~all the time.
__global__ __launch_bounds__(256, 4) void edge_pipe(
    const unsigned short* __restrict__ v1b, const unsigned short* __restrict__ v2b,
    const int* __restrict__ idx,
    const float* __restrict__ W1, const float* __restrict__ b1,
    const float* __restrict__ W2, const float* __restrict__ b2,
    float* __restrict__ out, int E, int ntiles)
{
    // 16 fragments (kc*4+jt) x 64 lanes x 8 bf16 = 16 KB, read as b128
    __shared__ __align__(16) unsigned short ldsW[16 * 64 * 8];

    const int tid  = threadIdx.x;
    const int wave = tid >> 6;
    const int lane = tid & 63;
    const int nn = lane & 15;   // edge-in-tile for A; column for B/D
    const int q  = lane >> 4;   // quad

    // stage W1 -> LDS in MFMA B-fragment layout:
    // frag f=(kc*4+jt), lane l holds t=0..7 of B[k=kc*32+(l>>4)*8+t][n=jt*16+(l&15)]
#pragma unroll
    for (int i = 0; i < 4; i++) {
        int p = tid * 4 + i;            // 0..1023 (frag,lane) pairs
        int f = p >> 6, l = p & 63;
        int kc = f >> 2, jt = f & 3, lq = (l >> 4) & 3, ln = l & 15;
        const float* wp = W1 + (size_t)(kc * 32 + lq * 8) * 64 + jt * 16 + ln;
        uint4 wv;
        wv.x = (unsigned)f2bf(wp[0 * 64]) | ((unsigned)f2bf(wp[1 * 64]) << 16);
        wv.y = (unsigned)f2bf(wp[2 * 64]) | ((unsigned)f2bf(wp[3 * 64]) << 16);
        wv.z = (unsigned)f2bf(wp[4 * 64]) | ((unsigned)f2bf(wp[5 * 64]) << 16);
        wv.w = (unsigned)f2bf(wp[6 * 64]) | ((unsigned)f2bf(wp[7 * 64]) << 16);
        *(uint4*)&ldsW[p * 8] = wv;
    }
    __syncthreads();

    float bias1[4], w2v[4];
#pragma unroll
    for (int jt = 0; jt < 4; jt++) {
        bias1[jt] = b1[jt * 16 + nn];
        w2v[jt]   = W2[jt * 16 + nn];
    }
    const float b2v = b2[0];

    const int nwaves = gridDim.x * 4;
    int tile = blockIdx.x * 4 + wave;
    if (tile >= ntiles) return;

    // pipeline prologue: idx + gathers for first tile
    int ee  = min(tile * 16 + nn, E - 1);
    int src = idx[ee];
    int dst = idx[E + ee];
    uint4 a[4], b[4];
    {
        const uint4* p1 = (const uint4*)(v1b + (size_t)src * 128);
        const uint4* p2 = (const uint4*)(v2b + (size_t)dst * 128);
#pragma unroll
        for (int kc = 0; kc < 4; kc++) { a[kc] = p1[kc * 4 + q]; b[kc] = p2[kc * 4 + q]; }
    }

    for (; tile < ntiles; tile += nwaves) {
        // issue next tile's idx load (in flight during product compute)
        const int tn = tile + nwaves;
        const int tt = (tn < ntiles) ? tn : tile;       // clamp: tail re-gathers self
        const int een  = min(tt * 16 + nn, E - 1);
        const int srcn = idx[een];
        const int dstn = idx[E + een];

        // products for current tile -> A fragments
        short8 Af[4];
#pragma unroll
        for (int kc = 0; kc < 4; kc++) {
            uint4 p;
            p.x = bfmul_trunc(a[kc].x, b[kc].x);
            p.y = bfmul_trunc(a[kc].y, b[kc].y);
            p.z = bfmul_trunc(a[kc].z, b[kc].z);
            p.w = bfmul_trunc(a[kc].w, b[kc].w);
            Af[kc] = __builtin_bit_cast(short8, p);
        }

        // issue next tile's gathers (raw regs now dead, reuse)
        {
            const uint4* p1 = (const uint4*)(v1b + (size_t)srcn * 128);
            const uint4* p2 = (const uint4*)(v2b + (size_t)dstn * 128);
#pragma unroll
            for (int kc = 0; kc < 4; kc++) { a[kc] = p1[kc * 4 + q]; b[kc] = p2[kc * 4 + q]; }
        }

        // MFMA: 16x 16x16x32 bf16, B fragments streamed from LDS
        f32x4 acc[4];
#pragma unroll
        for (int jt = 0; jt < 4; jt++) acc[jt] = (f32x4){0.f, 0.f, 0.f, 0.f};
#pragma unroll
        for (int kc = 0; kc < 4; kc++) {
#pragma unroll
            for (int jt = 0; jt < 4; jt++) {
                short8 Bf = *(const short8*)&ldsW[((kc * 4 + jt) * 64 + lane) * 8];
                acc[jt] = __builtin_amdgcn_mfma_f32_16x16x32_bf16(Af[kc], Bf, acc[jt], 0, 0, 0);
            }
        }

        // epilogue: h = ELU(acc + b1); partial = sum_n h * W2[n]
        float ps[4];
#pragma unroll
        for (int r = 0; r < 4; r++) {
            float s = 0.f;
#pragma unroll
            for (int jt = 0; jt < 4; jt++) {
                float h = acc[jt][r] + bias1[jt];
                h = (h > 0.f) ? h : (__expf(h) - 1.f);
                s += h * w2v[jt];
            }
            ps[r] = s;
        }
#pragma unroll
        for (int off = 1; off < 16; off <<= 1) {
#pragma unroll
            for (int r = 0; r < 4; r++)
                ps[r] += __shfl_xor(ps[r], off, 64);
        }
        if (nn == 0) {
#pragma unroll
            for (int r = 0; r < 4; r++) {
                int e = tile * 16 + q * 4 + r;   // D row = quad*4 + reg
                if (e < E) {
                    float x = ps[r] + b2v;
                    out[e] = 1.f / (1.f + __expf(-x));
                }
            }
        }
    }
}

// Fallback (ws too small): non-pipelined, gathers f32 z-arrays directly.
__global__ __launch_bounds__(256) void edge_f32(
    const float* __restrict__ zin, const float* __restrict__ zout,
    const float* __restrict__ zself,
    const int* __restrict__ idx,
    const float* __restrict__ W1, const float* __restrict__ b1,
    const float* __restrict__ W2, const float* __restrict__ b2,
    float* __restrict__ out, int E, int ntiles)
{
    const int wave = threadIdx.x >> 6;
    const int lane = threadIdx.x & 63;
    const int nn = lane & 15;
    const int q  = lane >> 4;

    short8 Bf[4][4];
#pragma unroll
    for (int kc = 0; kc < 4; kc++)
#pragma unroll
        for (int jt = 0; jt < 4; jt++) {
            short8 v;
#pragma unroll
            for (int t = 0; t < 8; t++)
                v[t] = (short)f2bf(W1[(kc * 32 + q * 8 + t) * 64 + jt * 16 + nn]);
            Bf[kc][jt] = v;
        }
    float bias1[4], w2v[4];
#pragma unroll
    for (int jt = 0; jt < 4; jt++) {
        bias1[jt] = b1[jt * 16 + nn];
        w2v[jt]   = W2[jt * 16 + nn];
    }
    const float b2v = b2[0];

    const int nwaves = gridDim.x * 4;
    for (int tile = blockIdx.x * 4 + wave; tile < ntiles; tile += nwaves) {
        const int ebase = tile * 16;
        const int ee  = min(ebase + nn, E - 1);
        const int src = idx[ee];
        const int dst = idx[E + ee];

        short8 Af[4];
        const float* po  = zout  + (size_t)src * 128 + q * 8;
        const float* ps1 = zself + (size_t)src * 128 + q * 8;
        const float* pi  = zin   + (size_t)dst * 128 + q * 8;
        const float* ps2 = zself + (size_t)dst * 128 + q * 8;
#pragma unroll
        for (int kc = 0; kc < 4; kc++) {
            float4 oa = *(const float4*)(po  + kc * 32), ob = *(const float4*)(po  + kc * 32 + 4);
            float4 sa = *(const float4*)(ps1 + kc * 32), sb = *(const float4*)(ps1 + kc * 32 + 4);
            float4 ia = *(const float4*)(pi  + kc * 32), ib = *(const float4*)(pi  + kc * 32 + 4);
            float4 ta = *(const float4*)(ps2 + kc * 32), tb = *(const float4*)(ps2 + kc * 32 + 4);
            uint4 p;
            p.x = pack_trunc((oa.x + sa.x) * (ia.x + ta.x), (oa.y + sa.y) * (ia.y + ta.y));
            p.y = pack_trunc((oa.z + sa.z) * (ia.z + ta.z), (oa.w + sa.w) * (ia.w + ta.w));
            p.z = pack_trunc((ob.x + sb.x) * (ib.x + tb.x), (ob.y + sb.y) * (ib.y + tb.y));
            p.w = pack_trunc((ob.z + sb.z) * (ib.z + tb.z), (ob.w + sb.w) * (ib.w + tb.w));
            Af[kc] = __builtin_bit_cast(short8, p);
        }

        f32x4 acc[4];
#pragma unroll
        for (int jt = 0; jt < 4; jt++) acc[jt] = (f32x4){0.f, 0.f, 0.f, 0.f};
#pragma unroll
        for (int kc = 0; kc < 4; kc++)
#pragma unroll
            for (int jt = 0; jt < 4; jt++)
                acc[jt] = __builtin_amdgcn_mfma_f32_16x16x32_bf16(Af[kc], Bf[kc][jt], acc[jt], 0, 0, 0);

        float ps[4];
#pragma unroll
        for (int r = 0; r < 4; r++) {
            float s = 0.f;
#pragma unroll
            for (int jt = 0; jt < 4; jt++) {
                float h = acc[jt][r] + bias1[jt];
                h = (h > 0.f) ? h : (__expf(h) - 1.f);
                s += h * w2v[jt];
            }
            ps[r] = s;
        }
#pragma unroll
        for (int off = 1; off < 16; off <<= 1) {
#pragma unroll
            for (int r = 0; r < 4; r++)
                ps[r] += __shfl_xor(ps[r], off, 64);
        }
        if (nn == 0) {
#pragma unroll
            for (int r = 0; r < 4; r++) {
                int e = ebase + q * 4 + r;
                if (e < E) {
                    float x = ps[r] + b2v;
                    out[e] = 1.f / (1.f + __expf(-x));
                }
            }
        }
    }
}

extern "C" void kernel_launch(void* const* d_in, const int* in_sizes, int n_in,
                              void* d_out, int out_size, void* d_ws, size_t ws_size,
                              hipStream_t stream)
{
    const float* zin   = (const float*)d_in[0];
    const float* zout  = (const float*)d_in[1];
    const float* zself = (const float*)d_in[2];
    const int*   idx   = (const int*)d_in[3];
    const float* W1    = (const float*)d_in[4];
    const float* b1    = (const float*)d_in[5];
    const float* W2    = (const float*)d_in[6];
    const float* b2    = (const float*)d_in[7];
    float* out = (float*)d_out;

    const int NC = in_sizes[0];          // N*C
    const int E  = in_sizes[3] / 2;
    const int ntiles = (E + 15) / 16;
    const size_t need = (size_t)NC * 4;  // two bf16 [N,C] arrays

    if (ws_size >= need) {
        unsigned short* v1b = (unsigned short*)d_ws;
        unsigned short* v2b = v1b + NC;
        const int n4 = NC / 4;
        const int nblocks = (n4 + 1023) / 1024;
        prep_kernel<<<nblocks, 256, 0, stream>>>(
            (const float4*)zin, (const float4*)zout, (const float4*)zself,
            (ushort4*)v1b, (ushort4*)v2b, n4);
        edge_pipe<<<1024, 256, 0, stream>>>(
            v1b, v2b, idx, W1, b1, W2, b2, out, E, ntiles);
    } else {
        edge_f32<<<2048, 256, 0, stream>>>(
            zin, zout, zself, idx, W1, b1, W2, b2, out, E, ntiles);
    }
}

// Round 8
// 217.466 us; speedup vs baseline: 1.0644x; 1.0529x over previous
//
#include <hip/hip_runtime.h>
#include <hip/hip_bf16.h>

typedef __attribute__((ext_vector_type(8))) short short8;
typedef __attribute__((ext_vector_type(4))) float f32x4;

__device__ __forceinline__ unsigned short f2bf(float f) {
    unsigned u = __float_as_uint(f);
    u += 0x7fffu + ((u >> 16) & 1u);   // RNE to bf16
    return (unsigned short)(u >> 16);
}

// product of two packed-bf16x2 words, repacked via truncation (1 v_perm)
__device__ __forceinline__ unsigned bfmul_trunc(unsigned a, unsigned b) {
    float al = __uint_as_float(a << 16);
    float ah = __uint_as_float(a & 0xffff0000u);
    float bl = __uint_as_float(b << 16);
    float bh = __uint_as_float(b & 0xffff0000u);
    unsigned pl = __float_as_uint(al * bl);
    unsigned ph = __float_as_uint(ah * bh);
    return __builtin_amdgcn_perm(ph, pl, 0x07060302u);  // hi16(ph)<<16 | hi16(pl)
}

__device__ __forceinline__ unsigned pack_trunc(float lo, float hi) {
    return __builtin_amdgcn_perm(__float_as_uint(hi), __float_as_uint(lo), 0x07060302u);
}

// v1b = bf16(z_out + z_self), v2b = bf16(z_in + z_self)
// z reads are NON-TEMPORAL (native ext-vector type for the builtin): 154 MB
// of read-once lines must not evict the 51 MB of v1b/v2b (written here,
// re-read by edge_pipe) from L2/L3.
__global__ __launch_bounds__(256) void prep_kernel(
    const f32x4* __restrict__ zin, const f32x4* __restrict__ zout,
    const f32x4* __restrict__ zself,
    ushort4* __restrict__ v1b, ushort4* __restrict__ v2b, int n4)
{
    const int base = blockIdx.x * 1024 + threadIdx.x;
    const bool full = (blockIdx.x + 1) * 1024 <= n4;   // whole block in-range
    if (full) {
        f32x4 o[4], s[4], z[4];
#pragma unroll
        for (int u = 0; u < 4; u++) {
            const int i = base + u * 256;
            o[u] = __builtin_nontemporal_load(zout + i);
            s[u] = __builtin_nontemporal_load(zself + i);
            z[u] = __builtin_nontemporal_load(zin + i);
        }
#pragma unroll
        for (int u = 0; u < 4; u++) {
            const int i = base + u * 256;
            ushort4 a, b;
            a.x = f2bf(o[u].x + s[u].x); a.y = f2bf(o[u].y + s[u].y);
            a.z = f2bf(o[u].z + s[u].z); a.w = f2bf(o[u].w + s[u].w);
            b.x = f2bf(z[u].x + s[u].x); b.y = f2bf(z[u].y + s[u].y);
            b.z = f2bf(z[u].z + s[u].z); b.w = f2bf(z[u].w + s[u].w);
            v1b[i] = a; v2b[i] = b;
        }
    } else {
#pragma unroll
        for (int u = 0; u < 4; u++) {
            const int i = base + u * 256;
            if (i < n4) {
                f32x4 o = __builtin_nontemporal_load(zout + i);
                f32x4 s = __builtin_nontemporal_load(zself + i);
                f32x4 z = __builtin_nontemporal_load(zin + i);
                ushort4 a, b;
                a.x = f2bf(o.x + s.x); a.y = f2bf(o.y + s.y);
                a.z = f2bf(o.z + s.z); a.w = f2bf(o.w + s.w);
                b.x = f2bf(z.x + s.x); b.y = f2bf(z.y + s.y);
                b.z = f2bf(z.z + s.z); b.w = f2bf(z.w + s.w);
                v1b[i] = a; v2b[i] = b;
            }
        }
    }
}

// Pipelined edge kernel. One wave per 16-edge tile per iteration.
// W1 in LDS (fragment-major, ds_read_b128); next tile's idx+gathers issued
// before current tile's MFMA/epilogue. Non-temporal out stores.
__global__ __launch_bounds__(256, 4) void edge_pipe(
    const unsigned short* __restrict__ v1b, const unsigned short* __restrict__ v2b,
    const int* __restrict__ idx,
    const float* __restrict__ W1, const float* __restrict__ b1,
    const float* __restrict__ W2, const float* __restrict__ b2,
    float* __restrict__ out, int E, int ntiles)
{
    // 16 fragments (kc*4+jt) x 64 lanes x 8 bf16 = 16 KB, read as b128
    __shared__ __align__(16) unsigned short ldsW[16 * 64 * 8];

    const int tid  = threadIdx.x;
    const int wave = tid >> 6;
    const int lane = tid & 63;
    const int nn = lane & 15;   // edge-in-tile for A; column for B/D
    const int q  = lane >> 4;   // quad

    // stage W1 -> LDS in MFMA B-fragment layout:
    // frag f=(kc*4+jt), lane l holds t=0..7 of B[k=kc*32+(l>>4)*8+t][n=jt*16+(l&15)]
#pragma unroll
    for (int i = 0; i < 4; i++) {
        int p = tid * 4 + i;            // 0..1023 (frag,lane) pairs
        int f = p >> 6, l = p & 63;
        int kc = f >> 2, jt = f & 3, lq = (l >> 4) & 3, ln = l & 15;
        const float* wp = W1 + (size_t)(kc * 32 + lq * 8) * 64 + jt * 16 + ln;
        uint4 wv;
        wv.x = (unsigned)f2bf(wp[0 * 64]) | ((unsigned)f2bf(wp[1 * 64]) << 16);
        wv.y = (unsigned)f2bf(wp[2 * 64]) | ((unsigned)f2bf(wp[3 * 64]) << 16);
        wv.z = (unsigned)f2bf(wp[4 * 64]) | ((unsigned)f2bf(wp[5 * 64]) << 16);
        wv.w = (unsigned)f2bf(wp[6 * 64]) | ((unsigned)f2bf(wp[7 * 64]) << 16);
        *(uint4*)&ldsW[p * 8] = wv;
    }
    __syncthreads();

    float bias1[4], w2v[4];
#pragma unroll
    for (int jt = 0; jt < 4; jt++) {
        bias1[jt] = b1[jt * 16 + nn];
        w2v[jt]   = W2[jt * 16 + nn];
    }
    const float b2v = b2[0];

    const int nwaves = gridDim.x * 4;
    int tile = blockIdx.x * 4 + wave;
    if (tile >= ntiles) return;

    // pipeline prologue: idx + gathers for first tile
    int ee  = min(tile * 16 + nn, E - 1);
    int src = idx[ee];
    int dst = idx[E + ee];
    uint4 a[4], b[4];
    {
        const uint4* p1 = (const uint4*)(v1b + (size_t)src * 128);
        const uint4* p2 = (const uint4*)(v2b + (size_t)dst * 128);
#pragma unroll
        for (int kc = 0; kc < 4; kc++) { a[kc] = p1[kc * 4 + q]; b[kc] = p2[kc * 4 + q]; }
    }

    for (; tile < ntiles; tile += nwaves) {
        // issue next tile's idx load (in flight during product compute)
        const int tn = tile + nwaves;
        const int tt = (tn < ntiles) ? tn : tile;       // clamp: tail re-gathers self
        const int een  = min(tt * 16 + nn, E - 1);
        const int srcn = idx[een];
        const int dstn = idx[E + een];

        // products for current tile -> A fragments
        short8 Af[4];
#pragma unroll
        for (int kc = 0; kc < 4; kc++) {
            uint4 p;
            p.x = bfmul_trunc(a[kc].x, b[kc].x);
            p.y = bfmul_trunc(a[kc].y, b[kc].y);
            p.z = bfmul_trunc(a[kc].z, b[kc].z);
            p.w = bfmul_trunc(a[kc].w, b[kc].w);
            Af[kc] = __builtin_bit_cast(short8, p);
        }

        // issue next tile's gathers (raw regs now dead, reuse)
        {
            const uint4* p1 = (const uint4*)(v1b + (size_t)srcn * 128);
            const uint4* p2 = (const uint4*)(v2b + (size_t)dstn * 128);
#pragma unroll
            for (int kc = 0; kc < 4; kc++) { a[kc] = p1[kc * 4 + q]; b[kc] = p2[kc * 4 + q]; }
        }

        // MFMA: 16x 16x16x32 bf16, B fragments streamed from LDS
        f32x4 acc[4];
#pragma unroll
        for (int jt = 0; jt < 4; jt++) acc[jt] = (f32x4){0.f, 0.f, 0.f, 0.f};
#pragma unroll
        for (int kc = 0; kc < 4; kc++) {
#pragma unroll
            for (int jt = 0; jt < 4; jt++) {
                short8 Bf = *(const short8*)&ldsW[((kc * 4 + jt) * 64 + lane) * 8];
                acc[jt] = __builtin_amdgcn_mfma_f32_16x16x32_bf16(Af[kc], Bf, acc[jt], 0, 0, 0);
            }
        }

        // epilogue: h = ELU(acc + b1); partial = sum_n h * W2[n]
        float ps[4];
#pragma unroll
        for (int r = 0; r < 4; r++) {
            float s = 0.f;
#pragma unroll
            for (int jt = 0; jt < 4; jt++) {
                float h = acc[jt][r] + bias1[jt];
                h = (h > 0.f) ? h : (__expf(h) - 1.f);
                s += h * w2v[jt];
            }
            ps[r] = s;
        }
#pragma unroll
        for (int off = 1; off < 16; off <<= 1) {
#pragma unroll
            for (int r = 0; r < 4; r++)
                ps[r] += __shfl_xor(ps[r], off, 64);
        }
        if (nn == 0) {
#pragma unroll
            for (int r = 0; r < 4; r++) {
                int e = tile * 16 + q * 4 + r;   // D row = quad*4 + reg
                if (e < E) {
                    float x = ps[r] + b2v;
                    __builtin_nontemporal_store(1.f / (1.f + __expf(-x)), out + e);
                }
            }
        }
    }
}

// Fallback (ws too small): non-pipelined, gathers f32 z-arrays directly.
__global__ __launch_bounds__(256) void edge_f32(
    const float* __restrict__ zin, const float* __restrict__ zout,
    const float* __restrict__ zself,
    const int* __restrict__ idx,
    const float* __restrict__ W1, const float* __restrict__ b1,
    const float* __restrict__ W2, const float* __restrict__ b2,
    float* __restrict__ out, int E, int ntiles)
{
    const int wave = threadIdx.x >> 6;
    const int lane = threadIdx.x & 63;
    const int nn = lane & 15;
    const int q  = lane >> 4;

    short8 Bf[4][4];
#pragma unroll
    for (int kc = 0; kc < 4; kc++)
#pragma unroll
        for (int jt = 0; jt < 4; jt++) {
            short8 v;
#pragma unroll
            for (int t = 0; t < 8; t++)
                v[t] = (short)f2bf(W1[(kc * 32 + q * 8 + t) * 64 + jt * 16 + nn]);
            Bf[kc][jt] = v;
        }
    float bias1[4], w2v[4];
#pragma unroll
    for (int jt = 0; jt < 4; jt++) {
        bias1[jt] = b1[jt * 16 + nn];
        w2v[jt]   = W2[jt * 16 + nn];
    }
    const float b2v = b2[0];

    const int nwaves = gridDim.x * 4;
    for (int tile = blockIdx.x * 4 + wave; tile < ntiles; tile += nwaves) {
        const int ebase = tile * 16;
        const int ee  = min(ebase + nn, E - 1);
        const int src = idx[ee];
        const int dst = idx[E + ee];

        short8 Af[4];
        const float* po  = zout  + (size_t)src * 128 + q * 8;
        const float* ps1 = zself + (size_t)src * 128 + q * 8;
        const float* pi  = zin   + (size_t)dst * 128 + q * 8;
        const float* ps2 = zself + (size_t)dst * 128 + q * 8;
#pragma unroll
        for (int kc = 0; kc < 4; kc++) {
            float4 oa = *(const float4*)(po  + kc * 32), ob = *(const float4*)(po  + kc * 32 + 4);
            float4 sa = *(const float4*)(ps1 + kc * 32), sb = *(const float4*)(ps1 + kc * 32 + 4);
            float4 ia = *(const float4*)(pi  + kc * 32), ib = *(const float4*)(pi  + kc * 32 + 4);
            float4 ta = *(const float4*)(ps2 + kc * 32), tb = *(const float4*)(ps2 + kc * 32 + 4);
            uint4 p;
            p.x = pack_trunc((oa.x + sa.x) * (ia.x + ta.x), (oa.y + sa.y) * (ia.y + ta.y));
            p.y = pack_trunc((oa.z + sa.z) * (ia.z + ta.z), (oa.w + sa.w) * (ia.w + ta.w));
            p.z = pack_trunc((ob.x + sb.x) * (ib.x + tb.x), (ob.y + sb.y) * (ib.y + tb.y));
            p.w = pack_trunc((ob.z + sb.z) * (ib.z + tb.z), (ob.w + sb.w) * (ib.w + tb.w));
            Af[kc] = __builtin_bit_cast(short8, p);
        }

        f32x4 acc[4];
#pragma unroll
        for (int jt = 0; jt < 4; jt++) acc[jt] = (f32x4){0.f, 0.f, 0.f, 0.f};
#pragma unroll
        for (int kc = 0; kc < 4; kc++)
#pragma unroll
            for (int jt = 0; jt < 4; jt++)
                acc[jt] = __builtin_amdgcn_mfma_f32_16x16x32_bf16(Af[kc], Bf[kc][jt], acc[jt], 0, 0, 0);

        float ps[4];
#pragma unroll
        for (int r = 0; r < 4; r++) {
            float s = 0.f;
#pragma unroll
            for (int jt = 0; jt < 4; jt++) {
                float h = acc[jt][r] + bias1[jt];
                h = (h > 0.f) ? h : (__expf(h) - 1.f);
                s += h * w2v[jt];
            }
            ps[r] = s;
        }
#pragma unroll
        for (int off = 1; off < 16; off <<= 1) {
#pragma unroll
            for (int r = 0; r < 4; r++)
                ps[r] += __shfl_xor(ps[r], off, 64);
        }
        if (nn == 0) {
#pragma unroll
            for (int r = 0; r < 4; r++) {
                int e = ebase + q * 4 + r;
                if (e < E) {
                    float x = ps[r] + b2v;
                    out[e] = 1.f / (1.f + __expf(-x));
                }
            }
        }
    }
}

extern "C" void kernel_launch(void* const* d_in, const int* in_sizes, int n_in,
                              void* d_out, int out_size, void* d_ws, size_t ws_size,
                              hipStream_t stream)
{
    const float* zin   = (const float*)d_in[0];
    const float* zout  = (const float*)d_in[1];
    const float* zself = (const float*)d_in[2];
    const int*   idx   = (const int*)d_in[3];
    const float* W1    = (const float*)d_in[4];
    const float* b1    = (const float*)d_in[5];
    const float* W2    = (const float*)d_in[6];
    const float* b2    = (const float*)d_in[7];
    float* out = (float*)d_out;

    const int NC = in_sizes[0];          // N*C
    const int E  = in_sizes[3] / 2;
    const int ntiles = (E + 15) / 16;
    const size_t need = (size_t)NC * 4;  // two bf16 [N,C] arrays

    if (ws_size >= need) {
        unsigned short* v1b = (unsigned short*)d_ws;
        unsigned short* v2b = v1b + NC;
        const int n4 = NC / 4;
        const int nblocks = (n4 + 1023) / 1024;
        prep_kernel<<<nblocks, 256, 0, stream>>>(
            (const f32x4*)zin, (const f32x4*)zout, (const f32x4*)zself,
            (ushort4*)v1b, (ushort4*)v2b, n4);
        edge_pipe<<<1024, 256, 0, stream>>>(
            v1b, v2b, idx, W1, b1, W2, b2, out, E, ntiles);
    } else {
        edge_f32<<<2048, 256, 0, stream>>>(
            zin, zout, zself, idx, W1, b1, W2, b2, out, E, ntiles);
    }
}